// Round 7
// baseline (450.331 us; speedup 1.0000x reference)
//
#include <hip/hip_runtime.h>

#define B_ 256
#define T_ 512
#define F_ 64
#define U_ 128

typedef _Float16 h2v __attribute__((ext_vector_type(2)));
union U32H2 { unsigned u; h2v h; };

__device__ __forceinline__ float fdot2(unsigned a, unsigned b, float c) {
  U32H2 x, y; x.u = a; y.u = b;
  return __builtin_amdgcn_fdot2(x.h, y.h, c, false);
}
__device__ __forceinline__ unsigned packh2(float a, float b) {
  U32H2 r; r.h[0] = (_Float16)a; r.h[1] = (_Float16)b; return r.u;
}
// lane-pair sum: quad_perm [1,0,3,2] exchange + add (both lanes get the pair total)
__device__ __forceinline__ float pairsum(float v) {
  int t = __builtin_amdgcn_update_dpp(0, __float_as_int(v), 0xB1, 0xF, 0xF, true);
  return v + __int_as_float(t);
}
__device__ __forceinline__ float fast_sig(float x) {
  return __builtin_amdgcn_rcpf(1.0f + __expf(-x));
}
__device__ __forceinline__ float fast_tanh(float x) {
  return fmaf(-2.0f, __builtin_amdgcn_rcpf(1.0f + __expf(2.0f * x)), 1.0f);
}

#define D4(acc, Hv, Wr, o)                                        \
  acc = fdot2(Hv.x, Wr[(o)], acc);                                \
  acc = fdot2(Hv.y, Wr[(o) + 1], acc);                            \
  acc = fdot2(Hv.z, Wr[(o) + 2], acc);                            \
  acc = fdot2(Hv.w, Wr[(o) + 3], acc);

__global__ __launch_bounds__(256, 1)
__attribute__((amdgpu_waves_per_eu(1, 1)))
void grud_kernel(
    const float* __restrict__ x, const float* __restrict__ m,
    const float* __restrict__ delta_t,
    const float* __restrict__ Wz_, const float* __restrict__ Uz, const float* __restrict__ bz,
    const float* __restrict__ Wr_, const float* __restrict__ Ur, const float* __restrict__ br,
    const float* __restrict__ Wh_, const float* __restrict__ Uh, const float* __restrict__ bh,
    const float* __restrict__ gxd, const float* __restrict__ ghd,
    const float* __restrict__ mi,
    float* __restrict__ out)
{
  const int tid = threadIdx.x;
  const int b   = blockIdx.x;
  const int w   = tid >> 6;        // wave id 0..3
  const int l   = tid & 63;        // lane
  const int c   = 32 * w + (l >> 1);  // owned output column (0..127)
  const int p   = l & 1;           // k-half: covers k in [64p, 64p+64)
  const bool ev = (p == 0);

  __shared__ float  s_dt[520];
  __shared__ __align__(16) ushort s_x16[4][64];   // decayed-x fp16 ring
  __shared__ __align__(16) ushort s_hd16[128];    // h_dec fp16
  __shared__ __align__(16) ushort s_rh16[128];    // r*h_dec fp16

  // ---- weights: columns into registers (fp16 pairs along k) ----
  unsigned uz[32], ur[32], uh[32];   // U rows [64p+2j, 64p+2j+1], col c
  unsigned wz[16], wr[16], wh[16];   // W rows [32p+2j, 32p+2j+1], col c
#pragma unroll
  for (int j = 0; j < 32; ++j) {
    const int k0 = 64 * p + 2 * j;
    uz[j] = packh2(Uz[k0 * U_ + c], Uz[(k0 + 1) * U_ + c]);
    ur[j] = packh2(Ur[k0 * U_ + c], Ur[(k0 + 1) * U_ + c]);
    uh[j] = packh2(Uh[k0 * U_ + c], Uh[(k0 + 1) * U_ + c]);
  }
#pragma unroll
  for (int j = 0; j < 16; ++j) {
    const int f0 = 32 * p + 2 * j;
    wz[j] = packh2(Wz_[f0 * U_ + c], Wz_[(f0 + 1) * U_ + c]);
    wr[j] = packh2(Wr_[f0 * U_ + c], Wr_[(f0 + 1) * U_ + c]);
    wh[j] = packh2(Wh_[f0 * U_ + c], Wh_[(f0 + 1) * U_ + c]);
  }
  const float bzc = bz[c], brc = br[c], bhc = bh[c];
  const float negg = -fmaxf(ghd[c], 0.0f);

  // staging lanes: l<16 of each wave owns feature f = 16w + l
  const int f_mine = 16 * w + l;
  float gxf = 0.0f, mif = 0.0f;
  if (l < 16) { gxf = -fmaxf(gxd[f_mine], 0.0f); mif = mi[f_mine]; }

  // ---- dt preload + state init ----
  {
    const float* dtb = delta_t + (size_t)b * T_;
    s_dt[tid]       = dtb[tid];
    s_dt[tid + 256] = dtb[tid + 256];
    if (tid < 8) s_dt[512 + tid] = 0.0f;
  }
  if (tid < 64) ((unsigned*)s_hd16)[tid] = 0u;   // h0 = 0
  __syncthreads();

  // ---- stage x_dec for ts=0,1 ----
#pragma unroll
  for (int ts = 0; ts < 2; ++ts) {
    if (l < 16) {
      const float xv = x[((size_t)(b * T_ + ts)) * F_ + f_mine];
      const float mv = m[((size_t)(b * T_ + ts)) * F_ + f_mine];
      const float gx = __expf(gxf * s_dt[ts]);
      const float xd = fmaf(mv, xv, (1.0f - mv) * (gx * xv + (1.0f - gx) * mif));
      ((_Float16*)s_x16[ts & 3])[f_mine] = (_Float16)xd;
    }
  }
  __syncthreads();

  // ---- x-projection partials for ts=0 (kept unreduced in regs) ----
  float axz, axr, axh;
  {
    const uint4* xp = (const uint4*)(s_x16[0] + 32 * p);
    float a0 = 0.f, a1 = 0.f, a2 = 0.f;
#pragma unroll
    for (int q = 0; q < 4; ++q) {
      const uint4 Xv = xp[q];
      D4(a0, Xv, wz, 4 * q) D4(a1, Xv, wr, 4 * q) D4(a2, Xv, wh, 4 * q)
    }
    axz = a0; axr = a1; axh = a2;
  }

  float hd_own = 0.0f;   // fp32 h_dec for column c (duplicated in lane pair)

#pragma unroll 1
  for (int tc = 0; tc < T_; ++tc) {
    const int ts = tc + 2;
    // issue next-stage global loads early (consumed at end of window C)
    float xv = 0.f, mv = 0.f;
    if (l < 16 && ts < T_) {
      xv = x[((size_t)(b * T_ + ts)) * F_ + f_mine];
      mv = m[((size_t)(b * T_ + ts)) * F_ + f_mine];
    }

    // ================= window B: z, r =================
    float az = axz, ar = axr;
    {
      const uint4* hp = (const uint4*)(s_hd16 + 64 * p);
#pragma unroll
      for (int jj = 0; jj < 8; ++jj) {
        const uint4 Hv = hp[jj];
        D4(az, Hv, uz, 4 * jj) D4(ar, Hv, ur, 4 * jj)
      }
    }
    az = pairsum(az) + bzc;
    ar = pairsum(ar) + brc;
    const float z = fast_sig(az);
    const float r = fast_sig(ar);
    if (ev) ((_Float16*)s_rh16)[c] = (_Float16)(r * hd_own);
    __syncthreads();

    // ================= window C: candidate + update =================
    float ah = axh;
    {
      const uint4* rp = (const uint4*)(s_rh16 + 64 * p);
#pragma unroll
      for (int jj = 0; jj < 8; ++jj) {
        const uint4 Rv = rp[jj];
        D4(ah, Rv, uh, 4 * jj)
      }
    }
    ah = pairsum(ah) + bhc;
    const float hh = fast_tanh(ah);
    const float hn = fmaf(z, hh - hd_own, hd_own);
    if (ev) out[((size_t)(b * T_ + tc)) * U_ + c] = hn;
    hd_own = __expf(negg * s_dt[tc + 1]) * hn;
    if (ev) ((_Float16*)s_hd16)[c] = (_Float16)hd_own;

    // next-step x-projection partials (independent work: fills rh-read latency)
    if (tc + 1 < T_) {
      const uint4* xp = (const uint4*)(s_x16[(tc + 1) & 3] + 32 * p);
      float a0 = 0.f, a1 = 0.f, a2 = 0.f;
#pragma unroll
      for (int q = 0; q < 4; ++q) {
        const uint4 Xv = xp[q];
        D4(a0, Xv, wz, 4 * q) D4(a1, Xv, wr, 4 * q) D4(a2, Xv, wh, 4 * q)
      }
      axz = a0; axr = a1; axh = a2;
    }

    // finish staging of ts = tc+2 (loads issued at top of step)
    if (l < 16 && ts < T_) {
      const float gx = __expf(gxf * s_dt[ts]);
      const float xd = fmaf(mv, xv, (1.0f - mv) * (gx * xv + (1.0f - gx) * mif));
      ((_Float16*)s_x16[ts & 3])[f_mine] = (_Float16)xd;
    }
    __syncthreads();
  }
}

extern "C" void kernel_launch(void* const* d_in, const int* in_sizes, int n_in,
                              void* d_out, int out_size, void* d_ws, size_t ws_size,
                              hipStream_t stream) {
  const float* x   = (const float*)d_in[0];
  const float* m   = (const float*)d_in[1];
  const float* dt  = (const float*)d_in[2];
  const float* Wz  = (const float*)d_in[3];
  const float* Uz  = (const float*)d_in[4];
  const float* bz  = (const float*)d_in[5];
  const float* Wr  = (const float*)d_in[6];
  const float* Ur  = (const float*)d_in[7];
  const float* br  = (const float*)d_in[8];
  const float* Wh  = (const float*)d_in[9];
  const float* Uh  = (const float*)d_in[10];
  const float* bh  = (const float*)d_in[11];
  const float* gxd = (const float*)d_in[12];
  const float* ghd = (const float*)d_in[13];
  const float* mi  = (const float*)d_in[14];

  grud_kernel<<<dim3(B_), dim3(256), 0, stream>>>(
      x, m, dt, Wz, Uz, bz, Wr, Ur, br, Wh, Uh, bh, gxd, ghd, mi, (float*)d_out);
}

// Round 8
// 365.111 us; speedup vs baseline: 1.2334x; 1.2334x over previous
//
#include <hip/hip_runtime.h>

#define B_ 256
#define T_ 512
#define F_ 64
#define U_ 128

typedef _Float16 h2v __attribute__((ext_vector_type(2)));
union U32H2 { unsigned u; h2v h; };

__device__ __forceinline__ float fdot2(unsigned a, unsigned b, float c) {
  U32H2 x, y; x.u = a; y.u = b;
  return __builtin_amdgcn_fdot2(x.h, y.h, c, false);
}
__device__ __forceinline__ unsigned packh2(float a, float b) {
  U32H2 r; r.h[0] = (_Float16)a; r.h[1] = (_Float16)b; return r.u;
}
// lane-pair sum via quad_perm [1,0,3,2]; both lanes get the pair total.
__device__ __forceinline__ float pairsum(float v) {
  int t = __builtin_amdgcn_update_dpp(0, __float_as_int(v), 0xB1, 0xF, 0xF, true);
  return v + __int_as_float(t);
}
__device__ __forceinline__ float fast_sig(float x) {
  return __builtin_amdgcn_rcpf(1.0f + __expf(-x));
}
__device__ __forceinline__ float fast_tanh(float x) {
  return fmaf(-2.0f, __builtin_amdgcn_rcpf(1.0f + __expf(2.0f * x)), 1.0f);
}

#define D4(acc, Hv, Wr, o)                                        \
  acc = fdot2(Hv.x, Wr[(o)], acc);                                \
  acc = fdot2(Hv.y, Wr[(o) + 1], acc);                            \
  acc = fdot2(Hv.z, Wr[(o) + 2], acc);                            \
  acc = fdot2(Hv.w, Wr[(o) + 3], acc);

__global__ __launch_bounds__(256, 1)
__attribute__((amdgpu_waves_per_eu(1, 1)))
void grud_kernel(
    const float* __restrict__ x, const float* __restrict__ m,
    const float* __restrict__ delta_t,
    const float* __restrict__ Wz_, const float* __restrict__ Uz, const float* __restrict__ bz,
    const float* __restrict__ Wr_, const float* __restrict__ Ur, const float* __restrict__ br,
    const float* __restrict__ Wh_, const float* __restrict__ Uh, const float* __restrict__ bh,
    const float* __restrict__ gxd, const float* __restrict__ ghd,
    const float* __restrict__ mi,
    float* __restrict__ out)
{
  const int tid = threadIdx.x;
  const int b   = blockIdx.x;
  const int w   = tid >> 6;           // wave 0..3
  const int l   = tid & 63;
  const int c   = 32 * w + (l >> 1);  // owned output column
  const int p   = l & 1;              // k-half
  const bool ev = (p == 0);

  __shared__ float  s_dt[520];
  __shared__ float  s_ghv[32 * U_];               // per-chunk decay factors
  __shared__ float  s_hist[32 * U_];              // per-chunk outputs (fp32)
  __shared__ __align__(16) ushort s_x16[32 * F_]; // per-chunk decayed x (fp16)
  __shared__ __align__(16) ushort s_hd16[U_];
  __shared__ __align__(16) ushort s_rh16[U_];
  __shared__ float  s_negg[U_];
  __shared__ float  s_gxf[F_];
  __shared__ float  s_mi[F_];

  // ---- weights into registers (fp16 pairs along k) ----
  unsigned uz[32], ur[32], uh[32];
  unsigned wz[16], wr[16], wh[16];
#pragma unroll
  for (int j = 0; j < 32; ++j) {
    const int k0 = 64 * p + 2 * j;
    uz[j] = packh2(Uz[k0 * U_ + c], Uz[(k0 + 1) * U_ + c]);
    ur[j] = packh2(Ur[k0 * U_ + c], Ur[(k0 + 1) * U_ + c]);
    uh[j] = packh2(Uh[k0 * U_ + c], Uh[(k0 + 1) * U_ + c]);
  }
#pragma unroll
  for (int j = 0; j < 16; ++j) {
    const int f0 = 32 * p + 2 * j;
    wz[j] = packh2(Wz_[f0 * U_ + c], Wz_[(f0 + 1) * U_ + c]);
    wr[j] = packh2(Wr_[f0 * U_ + c], Wr_[(f0 + 1) * U_ + c]);
    wh[j] = packh2(Wh_[f0 * U_ + c], Wh_[(f0 + 1) * U_ + c]);
  }
  const float bzc = bz[c], brc = br[c], bhc = bh[c];

  // ---- one-time LDS tables ----
  {
    const float* dtb = delta_t + (size_t)b * T_;
    s_dt[tid]       = dtb[tid];
    s_dt[tid + 256] = dtb[tid + 256];
    if (tid < 8)   s_dt[512 + tid] = 0.0f;
    if (tid < U_)  { s_negg[tid] = -fmaxf(ghd[tid], 0.0f); ((unsigned*)s_hd16)[tid >> 1] = 0u; }
    if (tid < F_)  { s_gxf[tid] = -fmaxf(gxd[tid], 0.0f); s_mi[tid] = mi[tid]; }
  }
  __syncthreads();

  float hd_own = 0.0f;
  float axz = 0.f, axr = 0.f, axh = 0.f;

  for (int t0 = 0; t0 < T_; t0 += 32) {
    // ======== chunk staging (bulk; only place with global loads) ========
#pragma unroll
    for (int i = 0; i < 2; ++i) {
      const int e4 = tid + 256 * i;            // 0..511 quad-groups
      const int t = e4 >> 4, f0 = (e4 & 15) << 2;
      const float dtv = s_dt[t0 + t];
      const float4 xv  = *(const float4*)(x + (size_t)(b * T_ + t0 + t) * F_ + f0);
      const float4 mv  = *(const float4*)(m + (size_t)(b * T_ + t0 + t) * F_ + f0);
      const float4 gv  = *(const float4*)(s_gxf + f0);
      const float4 miv = *(const float4*)(s_mi + f0);
      float gx, d0, d1, d2, d3;
      gx = __expf(gv.x * dtv);
      d0 = fmaf(mv.x, xv.x, (1.0f - mv.x) * (gx * xv.x + (1.0f - gx) * miv.x));
      gx = __expf(gv.y * dtv);
      d1 = fmaf(mv.y, xv.y, (1.0f - mv.y) * (gx * xv.y + (1.0f - gx) * miv.y));
      gx = __expf(gv.z * dtv);
      d2 = fmaf(mv.z, xv.z, (1.0f - mv.z) * (gx * xv.z + (1.0f - gx) * miv.z));
      gx = __expf(gv.w * dtv);
      d3 = fmaf(mv.w, xv.w, (1.0f - mv.w) * (gx * xv.w + (1.0f - gx) * miv.w));
      uint2 px; px.x = packh2(d0, d1); px.y = packh2(d2, d3);
      *(uint2*)(s_x16 + 4 * e4) = px;
    }
    // decay table for this chunk: ghv[t][c] = exp(-g_c * dt[t0+t+1])
#pragma unroll
    for (int i = 0; i < 16; ++i) {
      const int e = tid + 256 * i;             // 0..4095
      const int t = e >> 7, cc = e & 127;
      s_ghv[e] = __expf(s_negg[cc] * s_dt[t0 + t + 1]);
    }
    __syncthreads();

    // chunk prologue: x-projections for tc = 0
    {
      const uint4* xp = (const uint4*)(s_x16 + 32 * p);
      float a0 = 0.f, a1 = 0.f, a2 = 0.f;
#pragma unroll
      for (int q = 0; q < 4; ++q) {
        const uint4 Xv = xp[q];
        D4(a0, Xv, wz, 4 * q) D4(a1, Xv, wr, 4 * q) D4(a2, Xv, wh, 4 * q)
      }
      axz = a0; axr = a1; axh = a2;
    }

    // ======== 32 recurrent steps: LDS-only ========
#pragma unroll 1
    for (int tc = 0; tc < 32; ++tc) {
      // ---- window B: z, r ----
      float az0 = axz, az1 = 0.f, ar0 = axr, ar1 = 0.f;
      {
        const uint4* hp = (const uint4*)(s_hd16 + 64 * p);
#pragma unroll
        for (int jj = 0; jj < 4; ++jj) {
          const uint4 Ha = hp[jj], Hb = hp[jj + 4];
          D4(az0, Ha, uz, 4 * jj)  D4(az1, Hb, uz, 4 * jj + 16)
          D4(ar0, Ha, ur, 4 * jj)  D4(ar1, Hb, ur, 4 * jj + 16)
        }
      }
      const float az = pairsum(az0 + az1) + bzc;
      const float ar = pairsum(ar0 + ar1) + brc;
      const float z = fast_sig(az);
      const float r = fast_sig(ar);
      if (ev) ((_Float16*)s_rh16)[c] = (_Float16)(r * hd_own);
      __syncthreads();

      // ---- window C: candidate + update (+ next-step x-proj as filler) ----
      float ah0 = axh, ah1 = 0.f;
      {
        const uint4* rp = (const uint4*)(s_rh16 + 64 * p);
#pragma unroll
        for (int jj = 0; jj < 4; ++jj) {
          const uint4 Ra = rp[jj], Rb = rp[jj + 4];
          D4(ah0, Ra, uh, 4 * jj)  D4(ah1, Rb, uh, 4 * jj + 16)
        }
      }
      if (tc < 31) {
        const uint4* xp = (const uint4*)(s_x16 + (tc + 1) * F_ + 32 * p);
        float a0 = 0.f, a1 = 0.f, a2 = 0.f;
#pragma unroll
        for (int q = 0; q < 4; ++q) {
          const uint4 Xv = xp[q];
          D4(a0, Xv, wz, 4 * q) D4(a1, Xv, wr, 4 * q) D4(a2, Xv, wh, 4 * q)
        }
        axz = a0; axr = a1; axh = a2;
      }
      const float ah = pairsum(ah0 + ah1) + bhc;
      const float hh = fast_tanh(ah);
      const float hn = fmaf(z, hh - hd_own, hd_own);
      if (ev) s_hist[tc * U_ + c] = hn;
      hd_own = s_ghv[tc * U_ + c] * hn;
      if (ev) ((_Float16*)s_hd16)[c] = (_Float16)hd_own;
      __syncthreads();
    }

    // ======== flush chunk outputs (coalesced) ========
    {
      const float4* h4 = (const float4*)s_hist;
      float4* o4 = (float4*)(out + (size_t)(b * T_ + t0) * U_);
#pragma unroll
      for (int i = 0; i < 4; ++i) o4[tid + 256 * i] = h4[tid + 256 * i];
    }
  }
}

extern "C" void kernel_launch(void* const* d_in, const int* in_sizes, int n_in,
                              void* d_out, int out_size, void* d_ws, size_t ws_size,
                              hipStream_t stream) {
  const float* x   = (const float*)d_in[0];
  const float* m   = (const float*)d_in[1];
  const float* dt  = (const float*)d_in[2];
  const float* Wz  = (const float*)d_in[3];
  const float* Uz  = (const float*)d_in[4];
  const float* bz  = (const float*)d_in[5];
  const float* Wr  = (const float*)d_in[6];
  const float* Ur  = (const float*)d_in[7];
  const float* br  = (const float*)d_in[8];
  const float* Wh  = (const float*)d_in[9];
  const float* Uh  = (const float*)d_in[10];
  const float* bh  = (const float*)d_in[11];
  const float* gxd = (const float*)d_in[12];
  const float* ghd = (const float*)d_in[13];
  const float* mi  = (const float*)d_in[14];

  grud_kernel<<<dim3(B_), dim3(256), 0, stream>>>(
      x, m, dt, Wz, Uz, bz, Wr, Ur, br, Wh, Uh, bh, gxd, ghd, mi, (float*)d_out);
}